// Round 10
// baseline (402.350 us; speedup 1.0000x reference)
//
#include <hip/hip_runtime.h>

// Correlation cost volume: B=4, C=256, H=W=192, MAX_DISP=4 -> 81 displacements.
// out[b, dy*9+dx, y, x] = (1/C) * sum_c F[b,c,y,x] * Spad[b,c,y+dy-4,x+dx-4]
//
// R10: MFMA Gram-band kernel. For fixed (b,y,dy), out[dx,x] are the 9
//      diagonals of G[u,x] = sum_c S[c,v,u] * F[c,y,x]  (v=y+dy-4, u=x+dx-4),
//      computed as 16x16 u/x tiles with mfma_f32_16x16x32_bf16 (K=256).
//      3.5x padded-MFMA waste but the matrix pipe runs at ~2075 TF vs the
//      157 TF vector ALU the session has been plateaued on (~190us, no pipe
//      >52% -- latency-bound; R8/R9 falsified LDS-read & barrier theories).
//      Block = (3y)x(3dy)x(64x): 8 waves = (x-tile, u-half); wave owns 9 acc
//      tiles acc[yy][dd] (36 VGPR). S staged as 5 shared rows (y+dy-diagonal
//      sharing); operands staged in FRAGMENT ORDER via transposed c-gather
//      (8 coalesced dword loads -> bf16 -> 1 conflict-free ds_write_b128);
//      fragment read is base + lane*16B (linear). OOB u/v zero-stuffed in
//      LDS -> padding outputs become exact 0, no epilogue masking.

#define MAXD 4
#define WINW 9
#define NDISP 81

constexpr int B_ = 4, C_ = 256, H_ = 192, W_ = 192;
constexpr int PHW = H_ * W_;             // 36864
constexpr int YS = 3;                    // y rows per block
constexpr int DS = 3;                    // dy values per block
constexpr int XS = 64;                   // x cols per block
constexpr int VR = YS + DS - 1;          // 5 staged S rows
constexpr int NUT = 5;                   // u-tiles of 16 (80 u: x0-8 .. x0+72)
constexpr int KB = 32;                   // channels per K-step
constexpr int NK = C_ / KB;              // 8
constexpr int NTHREADS = 512;            // 8 waves

constexpr int S_USHORT = VR * NUT * 512; // 12800 bf16 (frag blocks of 512)
constexpr int F_USHORT = YS * 4 * 512;   // 6144 bf16
constexpr int LDS_USHORT = S_USHORT + F_USHORT;  // 18944 = 37,888 B
constexpr int S_TASKS = S_USHORT / 8;    // 1600 (8 bf16 per task)
constexpr int F_TASKS = F_USHORT / 8;    // 768

constexpr int NYS = H_ / YS;             // 64
constexpr int NDS = WINW / DS;           // 3
constexpr int NXS = W_ / XS;             // 3
constexpr int NBLK = B_ * NYS * NDS * NXS;  // 2304
constexpr int PER_XCD = NBLK / 8;        // 288 (exact)

typedef __attribute__((ext_vector_type(8))) short bf16x8;
typedef __attribute__((ext_vector_type(4))) float f32x4;

// float -> bf16 (round-to-nearest-even), bit pattern in low 16
__device__ __forceinline__ unsigned f2bf(float f) {
    unsigned u = __float_as_uint(f);
    return (u + 0x7FFFu + ((u >> 16) & 1u)) >> 16;
}

__global__ __launch_bounds__(NTHREADS, 4)
void corr_kernel(const float* __restrict__ F, const float* __restrict__ S,
                 float* __restrict__ O) {
    __shared__ __align__(16) unsigned short lds[LDS_USHORT];   // 37,888 B

    const int tid  = threadIdx.x;
    const int lane = tid & 63;
    const int wid  = tid >> 6;           // wave 0..7
    const int xt   = wid & 3;            // wave's x-tile (16 cols)
    const int uh   = wid >> 2;           // wave's u-half (0/1)
    const int utw  = xt + uh;            // wave's u-tile index 0..4

    // ---- XCD-bijective swizzle: 2304 = 8 x 288; xs fastest, so same-
    //      (b,ystrip) blocks (sharing F rows / S windows) are XCD-adjacent.
    const int id = blockIdx.x;
    const int lg = (id & 7) * PER_XCD + (id >> 3);
    const int xs     = lg % NXS;
    const int t1     = lg / NXS;
    const int dstrip = t1 % NDS;
    const int t2     = t1 / NDS;
    const int ystrip = t2 % NYS;
    const int b      = t2 / NYS;
    const int Y0 = ystrip * YS, D0 = dstrip * DS, x0 = xs * XS;
    const int vbase = Y0 + D0 - MAXD;    // first staged S row (may be <0)
    const int ubase = x0 - 8;            // first staged u (may be <0)

    const float* Fb = F + (long)b * C_ * PHW;
    const float* Sb = S + (long)b * C_ * PHW;

    // ---- chunk-invariant staging tasks ----
    // S: task t -> (vr, ut, khalf, u16); 8 bf16 = channels kh*8+j at (v,u).
    const float* sP[4]; int sL[4]; bool sOk[4], sAct[4];
    #pragma unroll
    for (int q = 0; q < 4; ++q) {
        const int t   = tid + q * NTHREADS;
        const bool a  = (t < S_TASKS);
        const int tt  = a ? t : 0;
        const int u16 = tt & 15;
        const int kh  = (tt >> 4) & 3;
        const int rest = tt >> 6;        // < 25
        const int ut  = rest % 5;
        const int vr  = rest / 5;
        const int v   = vbase + vr;
        const int u   = ubase + ut * 16 + u16;
        const bool inb = a && ((unsigned)v < (unsigned)H_) &&
                              ((unsigned)u < (unsigned)W_);
        sAct[q] = a;
        sOk[q]  = inb;
        sL[q]   = tt * 8;
        sP[q]   = Sb + (long)(kh * 8) * PHW + (long)(inb ? v : 0) * W_
                     + (inb ? u : 0);
    }
    // F: task t -> (yy, xt, khalf, x16); always in-bounds.
    const float* fP[2]; int fL[2]; bool fAct[2];
    #pragma unroll
    for (int q = 0; q < 2; ++q) {
        const int t   = tid + q * NTHREADS;
        const bool a  = (t < F_TASKS);
        const int tt  = a ? t : 0;
        const int x16 = tt & 15;
        const int kh  = (tt >> 4) & 3;
        const int rest = tt >> 6;        // < 12
        const int xtq = rest & 3;
        const int yy  = rest >> 2;
        fAct[q] = a;
        fL[q]   = S_USHORT + tt * 8;
        fP[q]   = Fb + (long)(kh * 8) * PHW + (long)(Y0 + yy) * W_
                     + (x0 + xtq * 16 + x16);
    }

    // ---- accumulators: 9 Gram tiles per wave ----
    f32x4 acc[3][3];
    #pragma unroll
    for (int yy = 0; yy < 3; ++yy)
        #pragma unroll
        for (int dd = 0; dd < 3; ++dd)
            acc[yy][dd] = (f32x4){0.f, 0.f, 0.f, 0.f};

    // ---- K loop: stage(32ch, fragment order) -> sync -> 9 MFMA -> sync ----
    for (int step = 0; step < NK; ++step) {
        const int c0 = step * KB;
        // stage S
        #pragma unroll
        for (int q = 0; q < 4; ++q) {
            if (!sAct[q]) continue;
            unsigned w0 = 0, w1 = 0, w2 = 0, w3 = 0;
            if (sOk[q]) {
                const float* p = sP[q] + (long)c0 * PHW;
                float f[8];
                #pragma unroll
                for (int j = 0; j < 8; ++j) f[j] = p[j * PHW];
                w0 = f2bf(f[0]) | (f2bf(f[1]) << 16);
                w1 = f2bf(f[2]) | (f2bf(f[3]) << 16);
                w2 = f2bf(f[4]) | (f2bf(f[5]) << 16);
                w3 = f2bf(f[6]) | (f2bf(f[7]) << 16);
            }
            uint4 v; v.x = w0; v.y = w1; v.z = w2; v.w = w3;
            *(uint4*)(&lds[sL[q]]) = v;
        }
        // stage F
        #pragma unroll
        for (int q = 0; q < 2; ++q) {
            if (!fAct[q]) continue;
            const float* p = fP[q] + (long)c0 * PHW;
            float f[8];
            #pragma unroll
            for (int j = 0; j < 8; ++j) f[j] = p[j * PHW];
            uint4 v;
            v.x = f2bf(f[0]) | (f2bf(f[1]) << 16);
            v.y = f2bf(f[2]) | (f2bf(f[3]) << 16);
            v.z = f2bf(f[4]) | (f2bf(f[5]) << 16);
            v.w = f2bf(f[6]) | (f2bf(f[7]) << 16);
            *(uint4*)(&lds[fL[q]]) = v;
        }
        __syncthreads();

        // fragment reads: linear, conflict-free (base + lane*16B)
        bf16x8 A[5], Bf[3];
        #pragma unroll
        for (int vr = 0; vr < 5; ++vr)
            A[vr] = *(const bf16x8*)(&lds[(vr * 5 + utw) * 512 + lane * 8]);
        #pragma unroll
        for (int yy = 0; yy < 3; ++yy)
            Bf[yy] = *(const bf16x8*)(&lds[S_USHORT + (yy * 4 + xt) * 512
                                           + lane * 8]);
        // D[u,x] += A(S)[u,k] * B(F)[k,x];  A-frag for (yy,dd) is row yy+dd
        #pragma unroll
        for (int yy = 0; yy < 3; ++yy)
            #pragma unroll
            for (int dd = 0; dd < 3; ++dd)
                acc[yy][dd] = __builtin_amdgcn_mfma_f32_16x16x32_bf16(
                    A[yy + dd], Bf[yy], acc[yy][dd], 0, 0, 0);

        if (step + 1 < NK) __syncthreads();
    }

    // ---- epilogue: scatter the 9 valid diagonals of each tile ----
    // C/D layout (m89-verified): col = lane&15 (=x16), row = (lane>>4)*4+reg.
    // dx = u - x + 4 = uh*16 + row - col - 4; valid iff 0 <= dx < 9.
    const float scale = 1.0f / (float)C_;
    const int col   = lane & 15;
    const int rowb  = (lane >> 4) * 4;
    const int x_abs = x0 + xt * 16 + col;
    #pragma unroll
    for (int r = 0; r < 4; ++r) {
        const int dx = uh * 16 + rowb + r - col - 4;
        if (0 <= dx && dx < WINW) {
            #pragma unroll
            for (int yy = 0; yy < 3; ++yy)
                #pragma unroll
                for (int dd = 0; dd < 3; ++dd) {
                    const int d = (D0 + dd) * WINW + dx;
                    O[((long)(b * NDISP + d) * H_ + (Y0 + yy)) * W_ + x_abs]
                        = acc[yy][dd][r] * scale;
                }
        }
    }
}

extern "C" void kernel_launch(void* const* d_in, const int* in_sizes, int n_in,
                              void* d_out, int out_size, void* d_ws, size_t ws_size,
                              hipStream_t stream) {
    const float* F = (const float*)d_in[0];
    const float* S = (const float*)d_in[1];
    float* O = (float*)d_out;
    dim3 grid(NBLK, 1, 1);   // 2304 eight-wave blocks
    dim3 block(NTHREADS);
    corr_kernel<<<grid, block, 0, stream>>>(F, S, O);
}